// Round 8
// baseline (1521.321 us; speedup 1.0000x reference)
//
#include <hip/hip_runtime.h>

// Net_4544075399853: x->20 linear, LSTMCell(20,20), 20->1 linear; B=8192, T=2048, fp32.
// R8: latency-bound fix — two independent 3-row LSTM groups per wave (6 rows/wave).
//  - Weights are row-independent => groups A and B SHARE the 80-VGPR whh2 copy.
//    Two independent per-step dependency chains interleave inside one wave: group B's
//    pk_fmas fill group A's ds_read/exp2 stall slots (and vice versa).
//  - 1366 single-wave workgroups; waves_per_eu(2,2) = 256-reg cap, zero spill pressure.
//  - v_pk_fma_f32 dots (40 pk/group/step), exp2-domain activations (log2e folded),
//    output lanes 60-62 compute out[] as their gate-0 dot. 1.25 KB dbuf LDS.

#define HID 20
#define RPG 3                 // rows per group
#define ROWS_PER_WAVE 6       // 2 groups
#define NTHREADS 64
#define L2E 1.4426950408889634f

typedef float v2f __attribute__((ext_vector_type(2)));

__device__ __forceinline__ float exp2_hw(float v) { return __builtin_amdgcn_exp2f(v); }
__device__ __forceinline__ float rcp_hw(float v)  { return __builtin_amdgcn_rcpf(v); }

__device__ __forceinline__ float sig_s(float gs) {            // gs = L2E*g -> sigmoid(g)
    return rcp_hw(1.0f + exp2_hw(-gs));
}
__device__ __forceinline__ float tanh_2Ls(float gs2) {        // gs2 = 2L*g -> 2L*tanh(g)
    return (2.0f * L2E) - (4.0f * L2E) * rcp_hw(1.0f + exp2_hw(gs2));
}
__device__ __forceinline__ float tanh_c(float cs) {           // cs = 2L*c -> tanh(c)
    return 1.0f - 2.0f * rcp_hw(1.0f + exp2_hw(cs));
}

__global__ __attribute__((amdgpu_flat_work_group_size(NTHREADS, NTHREADS),
                          amdgpu_waves_per_eu(2, 2)))
void lstm_wave(
        const float* __restrict__ x,     // [B, T]
        const float* __restrict__ W1,    // [20]
        const float* __restrict__ b1,    // [20]
        const float* __restrict__ W_ih,  // [80, 20]
        const float* __restrict__ W_hh,  // [80, 20]
        const float* __restrict__ b_ih,  // [80]
        const float* __restrict__ b_hh,  // [80]
        const float* __restrict__ W2,    // [20]
        const float* __restrict__ b2,    // [1]
        float* __restrict__ out,         // [B, T]
        const int B, const int T)
{
    const int lane = threadIdx.x;
    const int lrow = lane / HID;          // 0..3
    const int m    = lane % HID;          // 0..19
    const bool gatelane = (lane < 60);
    const bool outlane  = (lrow == 3) && (m < RPG);     // lanes 60,61,62
    const int rA = gatelane ? lrow : (outlane ? m : 0); // local row in group A
    const long rowbase = (long)blockIdx.x * ROWS_PER_WAVE;
    const long rowA = rowbase + rA;
    const long rowB = rowA + RPG;
    const long aA = (rowA < B) ? rowA : (long)(B - 1);
    const long aB = (rowB < B) ? rowB : (long)(B - 1);
    const bool ovA = outlane && (rowA < B);
    const bool ovB = outlane && (rowB < B);
    // LDS row slots: 0..2 = group A rows, 3..5 = group B rows, 6/7 = trash (lane 63)
    const int rsA = gatelane ? lrow : (outlane ? m : 6);
    const int rsB = gatelane ? (lrow + 3) : (outlane ? (m + 3) : 7);

    __shared__ __align__(16) float hbuf[2][8][HID];   // 1280 B

    // ---- phase 1: u, v (low live-set; weights not yet loaded) ----
    float u[4], v[4];
    if (gatelane) {
#pragma unroll
        for (int g = 0; g < 4; ++g) {
            const int j = g * HID + m;            // torch gate order i,f,g,o
            const float s = (g == 2) ? (2.0f * L2E) : L2E;
            float uu = 0.f, vv = 0.f;
#pragma unroll
            for (int k = 0; k < HID; ++k) {
                const float wi = W_ih[j * HID + k];
                uu += wi * W1[k];
                vv += wi * b1[k];
            }
            u[g] = s * uu;
            v[g] = s * (vv + b_ih[j] + b_hh[j]);
        }
    } else {
#pragma unroll
        for (int g = 0; g < 4; ++g) { u[g] = 0.f; v[g] = 0.f; }
        v[0] = b2[0];
    }

    // ---- phase 2: whh as 40 float2 pairs (scaled) — SHARED by groups A and B ----
    v2f whh2[4][HID / 2];
    if (gatelane) {
#pragma unroll
        for (int g = 0; g < 4; ++g) {
            const int j = g * HID + m;
            const float s = (g == 2) ? (2.0f * L2E) : L2E;
#pragma unroll
            for (int kk = 0; kk < HID / 2; ++kk) {
                v2f w;
                w.x = s * W_hh[j * HID + 2 * kk];
                w.y = s * W_hh[j * HID + 2 * kk + 1];
                whh2[g][kk] = w;
            }
        }
    } else {
#pragma unroll
        for (int kk = 0; kk < HID / 2; ++kk) {
            v2f w; w.x = W2[2 * kk]; w.y = W2[2 * kk + 1];
            whh2[0][kk] = w;
            whh2[1][kk] = (v2f)(0.f);
            whh2[2][kk] = (v2f)(0.f);
            whh2[3][kk] = (v2f)(0.f);
        }
    }

    // Opaque defs: prevent remat of the weight loads into the loop.
#pragma unroll
    for (int g = 0; g < 4; ++g)
#pragma unroll
        for (int kk = 0; kk < HID / 2; ++kk)
            asm volatile("" : "+v"(whh2[g][kk]));

    float csA = 0.f, csB = 0.f;   // c in 2*log2e-scaled domain, per group
    if (gatelane) {
        hbuf[0][lrow][m] = 0.f;  hbuf[0][lrow + 3][m] = 0.f;
        hbuf[1][lrow][m] = 0.f;  hbuf[1][lrow + 3][m] = 0.f;
    }
    __syncthreads();

    const float* __restrict__ xrowA = x + aA * T;
    const float* __restrict__ xrowB = x + aB * T;
    float* __restrict__ orowA = out + aA * T;
    float* __restrict__ orowB = out + aB * T;

    const float4* __restrict__ rdA0 = (const float4*)&hbuf[0][rsA][0];
    const float4* __restrict__ rdA1 = (const float4*)&hbuf[1][rsA][0];
    const float4* __restrict__ rdB0 = (const float4*)&hbuf[0][rsB][0];
    const float4* __restrict__ rdB1 = (const float4*)&hbuf[1][rsB][0];
    float* __restrict__ wrA0 = &hbuf[1][lrow][m];        // body A writes buf1
    float* __restrict__ wrB0 = &hbuf[1][(lrow + 3) & 7][m];
    float* __restrict__ wrA1 = &hbuf[0][lrow][m];        // body B writes buf0
    float* __restrict__ wrB1 = &hbuf[0][(lrow + 3) & 7][m];

    float xA_next = xrowA[0];
    float xB_next = xrowB[0];

#define STEP_BODY(RDA, RDB, WRA, WRB, OUTVALID_PREV, OUT_IDX)                    \
    {                                                                            \
        v2f qa0, qa1, qa2, qa3, qb0, qb1, qb2, qb3;                              \
        qa0.x = v[0] + xA * u[0]; qa0.y = 0.f;                                   \
        qa1.x = v[1] + xA * u[1]; qa1.y = 0.f;                                   \
        qa2.x = v[2] + xA * u[2]; qa2.y = 0.f;                                   \
        qa3.x = v[3] + xA * u[3]; qa3.y = 0.f;                                   \
        qb0.x = v[0] + xB * u[0]; qb0.y = 0.f;                                   \
        qb1.x = v[1] + xB * u[1]; qb1.y = 0.f;                                   \
        qb2.x = v[2] + xB * u[2]; qb2.y = 0.f;                                   \
        qb3.x = v[3] + xB * u[3]; qb3.y = 0.f;                                   \
        _Pragma("unroll")                                                        \
        for (int q = 0; q < 5; ++q) {                                            \
            const float4 fA = RDA[q];                                            \
            const float4 fB = RDB[q];                                            \
            v2f hA1; hA1.x = fA.x; hA1.y = fA.y;                                 \
            v2f hA2; hA2.x = fA.z; hA2.y = fA.w;                                 \
            v2f hB1; hB1.x = fB.x; hB1.y = fB.y;                                 \
            v2f hB2; hB2.x = fB.z; hB2.y = fB.w;                                 \
            qa0 = __builtin_elementwise_fma(whh2[0][2*q],   hA1, qa0);           \
            qb0 = __builtin_elementwise_fma(whh2[0][2*q],   hB1, qb0);           \
            qa1 = __builtin_elementwise_fma(whh2[1][2*q],   hA1, qa1);           \
            qb1 = __builtin_elementwise_fma(whh2[1][2*q],   hB1, qb1);           \
            qa2 = __builtin_elementwise_fma(whh2[2][2*q],   hA1, qa2);           \
            qb2 = __builtin_elementwise_fma(whh2[2][2*q],   hB1, qb2);           \
            qa3 = __builtin_elementwise_fma(whh2[3][2*q],   hA1, qa3);           \
            qb3 = __builtin_elementwise_fma(whh2[3][2*q],   hB1, qb3);           \
            qa0 = __builtin_elementwise_fma(whh2[0][2*q+1], hA2, qa0);           \
            qb0 = __builtin_elementwise_fma(whh2[0][2*q+1], hB2, qb0);           \
            qa1 = __builtin_elementwise_fma(whh2[1][2*q+1], hA2, qa1);           \
            qb1 = __builtin_elementwise_fma(whh2[1][2*q+1], hB2, qb1);           \
            qa2 = __builtin_elementwise_fma(whh2[2][2*q+1], hA2, qa2);           \
            qb2 = __builtin_elementwise_fma(whh2[2][2*q+1], hB2, qb2);           \
            qa3 = __builtin_elementwise_fma(whh2[3][2*q+1], hA2, qa3);           \
            qb3 = __builtin_elementwise_fma(whh2[3][2*q+1], hB2, qb3);           \
        }                                                                        \
        const float gA0 = qa0.x + qa0.y;                                         \
        const float gA1 = qa1.x + qa1.y;                                         \
        const float gA2 = qa2.x + qa2.y;                                         \
        const float gA3 = qa3.x + qa3.y;                                         \
        const float gB0 = qb0.x + qb0.y;                                         \
        const float gB1 = qb1.x + qb1.y;                                         \
        const float gB2 = qb2.x + qb2.y;                                         \
        const float gB3 = qb3.x + qb3.y;                                         \
        if ((OUTVALID_PREV) && ovA) orowA[OUT_IDX] = gA0;                        \
        if ((OUTVALID_PREV) && ovB) orowB[OUT_IDX] = gB0;                        \
        const float igA  = sig_s(gA0);                                           \
        const float igB  = sig_s(gB0);                                           \
        const float fgA  = sig_s(gA1);                                           \
        const float fgB  = sig_s(gB1);                                           \
        const float ggsA = tanh_2Ls(gA2);                                        \
        const float ggsB = tanh_2Ls(gB2);                                        \
        const float ogA  = sig_s(gA3);                                           \
        const float ogB  = sig_s(gB3);                                           \
        csA = fgA * csA + igA * ggsA;                                            \
        csB = fgB * csB + igB * ggsB;                                            \
        const float hnA = ogA * tanh_c(csA);                                     \
        const float hnB = ogB * tanh_c(csB);                                     \
        if (gatelane) { *(WRA) = hnA; *(WRB) = hnB; }                            \
        __syncthreads();                                                         \
    }

    for (int t = 0; t < T; t += 2) {
        // ---- body A: h_t in buf0 -> h_{t+1} in buf1 ----
        {
            const float xA = xA_next;
            const float xB = xB_next;
            xA_next = xrowA[t + 1];                 // t+1 <= T-1 always (T even)
            xB_next = xrowB[t + 1];
            STEP_BODY(rdA0, rdB0, wrA0, wrB0, t > 0, t - 1)
        }
        // ---- body B: h_{t+1} in buf1 -> h_{t+2} in buf0 ----
        {
            const float xA = xA_next;
            const float xB = xB_next;
            const int tn = (t + 2 < T) ? (t + 2) : (T - 1);   // uniform clamp
            xA_next = xrowA[tn];
            xB_next = xrowB[tn];
            STEP_BODY(rdA1, rdB1, wrA1, wrB1, true, t)
        }
    }
#undef STEP_BODY

    // epilogue: out[T-1] = b2 + W2 @ h_T ; h_T is in buf0 (T even)
    if (ovA) {
        float o = v[0];
#pragma unroll
        for (int q = 0; q < 5; ++q) {
            const float4 f = rdA0[q];
            o += whh2[0][2*q].x   * f.x + whh2[0][2*q].y   * f.y
               + whh2[0][2*q+1].x * f.z + whh2[0][2*q+1].y * f.w;
        }
        orowA[T - 1] = o;
    }
    if (ovB) {
        float o = v[0];
#pragma unroll
        for (int q = 0; q < 5; ++q) {
            const float4 f = rdB0[q];
            o += whh2[0][2*q].x   * f.x + whh2[0][2*q].y   * f.y
               + whh2[0][2*q+1].x * f.z + whh2[0][2*q+1].y * f.w;
        }
        orowB[T - 1] = o;
    }
}

extern "C" void kernel_launch(void* const* d_in, const int* in_sizes, int n_in,
                              void* d_out, int out_size, void* d_ws, size_t ws_size,
                              hipStream_t stream) {
    (void)n_in; (void)d_ws; (void)ws_size; (void)out_size;
    const float* x    = (const float*)d_in[0];
    const float* W1   = (const float*)d_in[1];
    const float* b1   = (const float*)d_in[2];
    const float* W_ih = (const float*)d_in[3];
    const float* W_hh = (const float*)d_in[4];
    const float* b_ih = (const float*)d_in[5];
    const float* b_hh = (const float*)d_in[6];
    const float* W2   = (const float*)d_in[7];
    const float* b2   = (const float*)d_in[8];
    float* out        = (float*)d_out;

    const int B = 8192;
    const int T = in_sizes[0] / B;  // 2048 (even)
    const int grid = (B + ROWS_PER_WAVE - 1) / ROWS_PER_WAVE;  // 1366 single-wave blocks

    lstm_wave<<<grid, NTHREADS, 0, stream>>>(x, W1, b1, W_ih, W_hh, b_ih, b_hh, W2, b2, out, B, T);
}

// Round 9
// 1205.533 us; speedup vs baseline: 1.2619x; 1.2619x over previous
//
#include <hip/hip_runtime.h>

// Net_4544075399853: x->20 linear, LSTMCell(20,20), 20->1 linear; B=8192, T=2048, fp32.
// R9: kill the per-step s_waitcnt vmcnt(0)+lgkmcnt(0)+s_barrier.
//  - R8 analysis: R7's per-wave step = 556 issue + ~908 STALL cycles. The stall is
//    __syncthreads: compiler emits full vmcnt(0) drain -> every step waits for the
//    global out-store and x-prefetch to retire. These are SINGLE-WAVE workgroups and
//    same-wave LDS ops execute in program order -> the barrier is pure loss. Removed.
//  - Per-thread alias analysis keeps ds_write -> ds_read order (the float4 h-read
//    overlaps the h-write address range for gate lanes), so no illegal reordering.
//  - Rest = R7: 3 rows/wave, 2731 single-wave blocks, whh as 40 float2 in regs
//    (asm-pinned), v_pk_fma_f32 dots, exp2-domain activations, out-lanes 60-62
//    compute out[] as their gate-0 dot, waves_per_eu(3,3).
//  - Gate accumulators split x2 (dep chain 10 -> 5).

#define HID 20
#define ROWS_PER_WAVE 3
#define NTHREADS 64
#define L2E 1.4426950408889634f

typedef float v2f __attribute__((ext_vector_type(2)));

__device__ __forceinline__ float exp2_hw(float v) { return __builtin_amdgcn_exp2f(v); }
__device__ __forceinline__ float rcp_hw(float v)  { return __builtin_amdgcn_rcpf(v); }

__device__ __forceinline__ float sig_s(float gs) {            // gs = L2E*g -> sigmoid(g)
    return rcp_hw(1.0f + exp2_hw(-gs));
}
__device__ __forceinline__ float tanh_2Ls(float gs2) {        // gs2 = 2L*g -> 2L*tanh(g)
    return (2.0f * L2E) - (4.0f * L2E) * rcp_hw(1.0f + exp2_hw(gs2));
}
__device__ __forceinline__ float tanh_c(float cs) {           // cs = 2L*c -> tanh(c)
    return 1.0f - 2.0f * rcp_hw(1.0f + exp2_hw(cs));
}

__global__ __attribute__((amdgpu_flat_work_group_size(NTHREADS, NTHREADS),
                          amdgpu_waves_per_eu(3, 3)))
void lstm_wave(
        const float* __restrict__ x,     // [B, T]
        const float* __restrict__ W1,    // [20]
        const float* __restrict__ b1,    // [20]
        const float* __restrict__ W_ih,  // [80, 20]
        const float* __restrict__ W_hh,  // [80, 20]
        const float* __restrict__ b_ih,  // [80]
        const float* __restrict__ b_hh,  // [80]
        const float* __restrict__ W2,    // [20]
        const float* __restrict__ b2,    // [1]
        float* __restrict__ out,         // [B, T]
        const int B, const int T)
{
    const int lane = threadIdx.x;
    const int lrow = lane / HID;          // 0..3 (3 = special lanes 60-63)
    const int m    = lane % HID;          // 0..19
    const bool outlane = (lrow == 3) && (m < ROWS_PER_WAVE);   // lanes 60,61,62
    const int rslot = (lrow == 3) ? m : lrow;  // LDS row slot this lane READS
    const long rowbase = (long)blockIdx.x * ROWS_PER_WAVE;
    const long row = rowbase + ((lrow == 3) ? (long)((m < 3) ? m : 0) : (long)lrow);
    const long arow = (row < B) ? row : (B - 1);     // safe address for OOB/aux lanes
    const bool ovalid = outlane && (row < B);

    // [2 buffers][4 row slots (slot 3 = trash)][20 units]
    __shared__ __align__(16) float hbuf[2][ROWS_PER_WAVE + 1][HID];

    // ---- phase 1: u, v (low live-set; weights not yet loaded) ----
    float u[4], v[4];
    if (lrow < 3) {
#pragma unroll
        for (int g = 0; g < 4; ++g) {
            const int j = g * HID + m;            // torch gate order i,f,g,o
            const float s = (g == 2) ? (2.0f * L2E) : L2E;
            float uu = 0.f, vv = 0.f;
#pragma unroll
            for (int k = 0; k < HID; ++k) {
                const float wi = W_ih[j * HID + k];
                uu += wi * W1[k];
                vv += wi * b1[k];
            }
            u[g] = s * uu;
            v[g] = s * (vv + b_ih[j] + b_hh[j]);
        }
    } else {
#pragma unroll
        for (int g = 0; g < 4; ++g) { u[g] = 0.f; v[g] = 0.f; }
        v[0] = b2[0];
    }

    // ---- phase 2: whh as 40 float2 pairs (scaled), low live-set load ----
    v2f whh2[4][HID / 2];
    if (lrow < 3) {
#pragma unroll
        for (int g = 0; g < 4; ++g) {
            const int j = g * HID + m;
            const float s = (g == 2) ? (2.0f * L2E) : L2E;
#pragma unroll
            for (int kk = 0; kk < HID / 2; ++kk) {
                v2f w;
                w.x = s * W_hh[j * HID + 2 * kk];
                w.y = s * W_hh[j * HID + 2 * kk + 1];
                whh2[g][kk] = w;
            }
        }
    } else {
#pragma unroll
        for (int kk = 0; kk < HID / 2; ++kk) {
            v2f w; w.x = W2[2 * kk]; w.y = W2[2 * kk + 1];
            whh2[0][kk] = w;
            whh2[1][kk] = (v2f)(0.f);
            whh2[2][kk] = (v2f)(0.f);
            whh2[3][kk] = (v2f)(0.f);
        }
    }

    // Opaque defs: prevent remat of the weight loads into the loop.
#pragma unroll
    for (int g = 0; g < 4; ++g)
#pragma unroll
        for (int kk = 0; kk < HID / 2; ++kk)
            asm volatile("" : "+v"(whh2[g][kk]));

    float cs = 0.f;   // c in 2*log2e-scaled domain
    hbuf[0][lrow][m] = 0.f;
    hbuf[1][lrow][m] = 0.f;
    // NO barrier: single-wave workgroup; same-wave LDS ops are in program order.

    const float* __restrict__ xrow = x   + arow * T;
    float* __restrict__       orow = out + arow * T;

    const float4* __restrict__ rd0 = (const float4*)&hbuf[0][rslot][0];
    const float4* __restrict__ rd1 = (const float4*)&hbuf[1][rslot][0];
    float* __restrict__ wr0 = &hbuf[1][lrow][m];   // body A writes buf1
    float* __restrict__ wr1 = &hbuf[0][lrow][m];   // body B writes buf0

    float xv_next = xrow[0];

#define GATE_BODY(RD, WR, OUT_IDX_VALID, OUT_IDX)                               \
    {                                                                            \
        v2f a0a, a1a, a2a, a3a, a0b, a1b, a2b, a3b;                              \
        a0a.x = v[0] + xv * u[0]; a0a.y = 0.f;  a0b = (v2f)(0.f);                \
        a1a.x = v[1] + xv * u[1]; a1a.y = 0.f;  a1b = (v2f)(0.f);                \
        a2a.x = v[2] + xv * u[2]; a2a.y = 0.f;  a2b = (v2f)(0.f);                \
        a3a.x = v[3] + xv * u[3]; a3a.y = 0.f;  a3b = (v2f)(0.f);                \
        _Pragma("unroll")                                                        \
        for (int q = 0; q < 5; ++q) {                                            \
            const float4 f = RD[q];                                              \
            v2f hA; hA.x = f.x; hA.y = f.y;                                      \
            v2f hB; hB.x = f.z; hB.y = f.w;                                      \
            a0a = __builtin_elementwise_fma(whh2[0][2*q],   hA, a0a);            \
            a1a = __builtin_elementwise_fma(whh2[1][2*q],   hA, a1a);            \
            a2a = __builtin_elementwise_fma(whh2[2][2*q],   hA, a2a);            \
            a3a = __builtin_elementwise_fma(whh2[3][2*q],   hA, a3a);            \
            a0b = __builtin_elementwise_fma(whh2[0][2*q+1], hB, a0b);            \
            a1b = __builtin_elementwise_fma(whh2[1][2*q+1], hB, a1b);            \
            a2b = __builtin_elementwise_fma(whh2[2][2*q+1], hB, a2b);            \
            a3b = __builtin_elementwise_fma(whh2[3][2*q+1], hB, a3b);            \
        }                                                                        \
        const v2f s0 = a0a + a0b;                                                \
        const v2f s1 = a1a + a1b;                                                \
        const v2f s2 = a2a + a2b;                                                \
        const v2f s3 = a3a + a3b;                                                \
        const float g0 = s0.x + s0.y;                                            \
        const float g1 = s1.x + s1.y;                                            \
        const float g2 = s2.x + s2.y;                                            \
        const float g3 = s3.x + s3.y;                                            \
        if ((OUT_IDX_VALID) && ovalid) orow[OUT_IDX] = g0;                       \
        const float ig  = sig_s(g0);                                             \
        const float fg  = sig_s(g1);                                             \
        const float ggs = tanh_2Ls(g2);                                          \
        const float og  = sig_s(g3);                                             \
        cs = fg * cs + ig * ggs;                                                 \
        *(WR) = og * tanh_c(cs);                                                 \
    }

    for (int t = 0; t < T; t += 2) {
        // ---- body A: h_t in buf0 -> h_{t+1} in buf1 ----
        {
            const float xv = xv_next;
            xv_next = xrow[t + 1];                 // t+1 <= T-1 always (T even)
            GATE_BODY(rd0, wr0, t > 0, t - 1)
        }
        // ---- body B: h_{t+1} in buf1 -> h_{t+2} in buf0 ----
        {
            const float xv = xv_next;
            const int tn = (t + 2 < T) ? (t + 2) : (T - 1);   // uniform clamp
            xv_next = xrow[tn];
            GATE_BODY(rd1, wr1, true, t)
        }
    }
#undef GATE_BODY

    // epilogue: out[T-1] = b2 + W2 @ h_T ; h_T is in buf0 (T even)
    if (ovalid) {
        float o = v[0];
#pragma unroll
        for (int q = 0; q < 5; ++q) {
            const float4 f = rd0[q];
            o += whh2[0][2*q].x   * f.x + whh2[0][2*q].y   * f.y
               + whh2[0][2*q+1].x * f.z + whh2[0][2*q+1].y * f.w;
        }
        orow[T - 1] = o;
    }
}

extern "C" void kernel_launch(void* const* d_in, const int* in_sizes, int n_in,
                              void* d_out, int out_size, void* d_ws, size_t ws_size,
                              hipStream_t stream) {
    (void)n_in; (void)d_ws; (void)ws_size; (void)out_size;
    const float* x    = (const float*)d_in[0];
    const float* W1   = (const float*)d_in[1];
    const float* b1   = (const float*)d_in[2];
    const float* W_ih = (const float*)d_in[3];
    const float* W_hh = (const float*)d_in[4];
    const float* b_ih = (const float*)d_in[5];
    const float* b_hh = (const float*)d_in[6];
    const float* W2   = (const float*)d_in[7];
    const float* b2   = (const float*)d_in[8];
    float* out        = (float*)d_out;

    const int B = 8192;
    const int T = in_sizes[0] / B;  // 2048 (even)
    const int grid = (B + ROWS_PER_WAVE - 1) / ROWS_PER_WAVE;  // 2731 single-wave blocks

    lstm_wave<<<grid, NTHREADS, 0, stream>>>(x, W1, b1, W_ih, W_hh, b_ih, b_hh, W2, b2, out, B, T);
}